// Round 2
// baseline (9450.984 us; speedup 1.0000x reference)
//
#include <hip/hip_runtime.h>

typedef unsigned short u16;
typedef unsigned int u32;
typedef __attribute__((ext_vector_type(8))) short bf16x8;
typedef __attribute__((ext_vector_type(4))) float f32x4;

#define N_NODES 20000
#define N_EDGES 160000
#define DDIM    1000

__device__ __forceinline__ float b2f(u16 u) {
    union { u32 i; float f; } v; v.i = ((u32)u) << 16; return v.f;
}
__device__ __forceinline__ u16 f2b(float f) {
    union { float f; u32 i; } v; v.f = f;
    u32 r = v.i + 0x7FFFu + ((v.i >> 16) & 1u);
    return (u16)(r >> 16);
}
__device__ __forceinline__ u32 pack2(float a, float b) {
    return (u32)f2b(a) | ((u32)f2b(b) << 16);
}
__device__ __forceinline__ f32x4 mfma16(bf16x8 a, bf16x8 b, f32x4 c) {
    return __builtin_amdgcn_mfma_f32_16x16x32_bf16(a, b, c, 0, 0, 0);
}
__device__ __forceinline__ float sigmoidf_(float x) { return 1.0f / (1.0f + expf(-x)); }

// ---------------------------------------------------------------------------
// fp32 -> bf16 bulk convert (n % 4 == 0)
// ---------------------------------------------------------------------------
__global__ __launch_bounds__(256) void cvt_f32_bf16(const float* __restrict__ in,
                                                    u16* __restrict__ out, size_t n) {
    size_t i = ((size_t)blockIdx.x * 256 + threadIdx.x) * 4;
    if (i >= n) return;
    float4 v = *(const float4*)(in + i);
    u32 o[2] = {pack2(v.x, v.y), pack2(v.z, v.w)};
    *(uint2*)(out + i) = *(const uint2*)o;
}

// ---------------------------------------------------------------------------
// Transpose weight[l] (fp32 [k][n]) -> Wt (bf16 [n][k]), 3 layers
// ---------------------------------------------------------------------------
__global__ __launch_bounds__(256) void transpose_w(const float* __restrict__ W,
                                                   u16* __restrict__ Wt) {
    __shared__ u16 t[32][33];
    int l = blockIdx.z;
    int nb = blockIdx.x * 32, kb = blockIdx.y * 32;
    int x = threadIdx.x, y = threadIdx.y;  // block (32, 8)
    const float* Wl = W + (size_t)l * 1000000;
    u16* Wtl = Wt + (size_t)l * 1000000;
    for (int i = 0; i < 32; i += 8) {
        int k = kb + y + i, n = nb + x;
        t[y + i][x] = (k < DDIM && n < DDIM) ? f2b(Wl[(size_t)k * DDIM + n]) : (u16)0;
    }
    __syncthreads();
    for (int i = 0; i < 32; i += 8) {
        int n = nb + y + i, k = kb + x;
        if (n < DDIM && k < DDIM) Wtl[(size_t)n * DDIM + k] = t[x][y + i];
    }
}

// ---------------------------------------------------------------------------
// C[M,N] (bf16) = A[M,K] @ Bt[N,K]^T, fp32 accum. A is fp32 (a_f32=1) or bf16.
// 128x128 tile, BK=32, 4 waves of 64x64, mfma 16x16x32 bf16.
// ---------------------------------------------------------------------------
__global__ __launch_bounds__(256) void gemm_bt(const void* __restrict__ Av, int a_f32,
                                               const u16* __restrict__ Bt,
                                               u16* __restrict__ C,
                                               int M, int N, int K) {
    __shared__ u16 As[128 * 40];
    __shared__ u16 Bs[128 * 40];
    int tid = threadIdx.x;
    int wave = tid >> 6, lane = tid & 63;
    int wr = wave >> 1, wc = wave & 1;
    int m0 = blockIdx.x * 128, n0 = blockIdx.y * 128;
    f32x4 acc[4][4] = {};
    int lr = tid >> 2;          // 0..63
    int lk = (tid & 3) * 8;     // k-chunk of 8 within BK=32

    for (int k0 = 0; k0 < K; k0 += 32) {
        int gk = k0 + lk;
        bool kok = (gk < K);    // K % 8 == 0 -> chunk fully in or out
        for (int h = 0; h < 2; h++) {
            int r = lr + h * 64;
            uint4 va = {0, 0, 0, 0}, vb = {0, 0, 0, 0};
            int gm = m0 + r;
            if (gm < M && kok) {
                if (a_f32) {
                    const float* Ap = (const float*)Av + (size_t)gm * K + gk;
                    float4 v0 = *(const float4*)Ap;
                    float4 v1 = *(const float4*)(Ap + 4);
                    va.x = pack2(v0.x, v0.y); va.y = pack2(v0.z, v0.w);
                    va.z = pack2(v1.x, v1.y); va.w = pack2(v1.z, v1.w);
                } else {
                    va = *(const uint4*)((const u16*)Av + (size_t)gm * K + gk);
                }
            }
            *(uint4*)(&As[r * 40 + lk]) = va;
            int gn = n0 + r;
            if (gn < N && kok) vb = *(const uint4*)(Bt + (size_t)gn * K + gk);
            *(uint4*)(&Bs[r * 40 + lk]) = vb;
        }
        __syncthreads();
        int fr = lane & 15, fk = (lane >> 4) * 8;
        bf16x8 af[4], bfv[4];
        for (int i = 0; i < 4; i++)
            af[i] = *(const bf16x8*)(&As[(wr * 64 + i * 16 + fr) * 40 + fk]);
        for (int j = 0; j < 4; j++)
            bfv[j] = *(const bf16x8*)(&Bs[(wc * 64 + j * 16 + fr) * 40 + fk]);
        for (int i = 0; i < 4; i++)
            for (int j = 0; j < 4; j++)
                acc[i][j] = mfma16(af[i], bfv[j], acc[i][j]);
        __syncthreads();
    }

    int cc = lane & 15, cr4 = (lane >> 4) * 4;
    for (int i = 0; i < 4; i++)
        for (int j = 0; j < 4; j++) {
            int gn = n0 + wc * 64 + j * 16 + cc;
            if (gn >= N) continue;
            for (int r = 0; r < 4; r++) {
                int gm = m0 + wr * 64 + i * 16 + cr4 + r;
                if (gm < M) C[(size_t)gm * N + gn] = f2b(acc[i][j][r]);
            }
        }
}

// ---------------------------------------------------------------------------
// agg[dst] += m[src] * ew  (fp32 atomics). One block per edge; ew fp32, m bf16.
// ---------------------------------------------------------------------------
__global__ __launch_bounds__(256) void edge_scatter(const int* __restrict__ ei,
                                                    const float* __restrict__ ew,
                                                    const u16* __restrict__ m,
                                                    float* __restrict__ agg) {
    int e = blockIdx.x;
    int c = threadIdx.x;            // chunk of 4 features
    if (c >= 250) return;
    int src = ei[e];
    int dst = ei[N_EDGES + e];
    float w = ew[e];
    uint2 v = *(const uint2*)(m + (size_t)src * DDIM + c * 4);
    const u16* p = (const u16*)&v;
    float* base = agg + (size_t)dst * DDIM + c * 4;
    for (int i = 0; i < 4; i++) atomicAdd(base + i, b2f(p[i]) * w);
}

// ---------------------------------------------------------------------------
// Fused GRU: h_out(bf16) = GRU(aggF fp32, h (fp32 if h_f32 else bf16)).
// Block tile 64 rows x 64 gate-features; 6 weight slabs (ih/hh x r,z,n) bf16.
// ---------------------------------------------------------------------------
__global__ __launch_bounds__(256) void gru_fused(const float* __restrict__ aggF,
                                                 const void* __restrict__ hv, int h_f32,
                                                 const u16* __restrict__ wih,
                                                 const u16* __restrict__ whh,
                                                 const float* __restrict__ bih,
                                                 const float* __restrict__ bhh,
                                                 u16* __restrict__ h_out) {
    const int K = DDIM, N = DDIM, M = N_NODES;
    __shared__ u16 Sa[64 * 40];        // agg tile (bf16-converted)
    __shared__ u16 Sh[64 * 40];        // h tile
    __shared__ u16 Sb[6][64 * 40];     // ih_r, ih_z, ih_n, hh_r, hh_z, hh_n
    int tid = threadIdx.x;
    int wave = tid >> 6, lane = tid & 63;
    int wr = wave >> 1, wc = wave & 1;
    int m0 = blockIdx.x * 64, n0 = blockIdx.y * 64;
    f32x4 a_r[2][2] = {}, a_z[2][2] = {}, a_in[2][2] = {}, a_hn[2][2] = {};
    int lr = tid >> 2;
    int lk = (tid & 3) * 8;

    for (int k0 = 0; k0 < K; k0 += 32) {
        int gk = k0 + lk;
        bool kok = (gk < K);
        {
            int gm = m0 + lr;
            uint4 va = {0, 0, 0, 0}, vh = {0, 0, 0, 0};
            if (gm < M && kok) {
                const float* Ap = aggF + (size_t)gm * K + gk;
                float4 a0 = *(const float4*)Ap;
                float4 a1 = *(const float4*)(Ap + 4);
                va.x = pack2(a0.x, a0.y); va.y = pack2(a0.z, a0.w);
                va.z = pack2(a1.x, a1.y); va.w = pack2(a1.z, a1.w);
                if (h_f32) {
                    const float* Hp = (const float*)hv + (size_t)gm * K + gk;
                    float4 h0 = *(const float4*)Hp;
                    float4 h1 = *(const float4*)(Hp + 4);
                    vh.x = pack2(h0.x, h0.y); vh.y = pack2(h0.z, h0.w);
                    vh.z = pack2(h1.x, h1.y); vh.w = pack2(h1.z, h1.w);
                } else {
                    vh = *(const uint4*)((const u16*)hv + (size_t)gm * K + gk);
                }
            }
            *(uint4*)(&Sa[lr * 40 + lk]) = va;
            *(uint4*)(&Sh[lr * 40 + lk]) = vh;
        }
        {
            int gn = n0 + lr;
            bool nok = (gn < N);
            for (int g = 0; g < 3; g++) {
                uint4 vi = {0, 0, 0, 0}, vhh = {0, 0, 0, 0};
                if (nok && kok) {
                    vi  = *(const uint4*)(wih + (size_t)(g * 1000 + gn) * K + gk);
                    vhh = *(const uint4*)(whh + (size_t)(g * 1000 + gn) * K + gk);
                }
                *(uint4*)(&Sb[g][lr * 40 + lk]) = vi;
                *(uint4*)(&Sb[3 + g][lr * 40 + lk]) = vhh;
            }
        }
        __syncthreads();
        int fr = lane & 15, fk = (lane >> 4) * 8;
        bf16x8 aa[2], ah[2], bb[6][2];
        for (int i = 0; i < 2; i++) {
            aa[i] = *(const bf16x8*)(&Sa[(wr * 32 + i * 16 + fr) * 40 + fk]);
            ah[i] = *(const bf16x8*)(&Sh[(wr * 32 + i * 16 + fr) * 40 + fk]);
        }
        for (int q = 0; q < 6; q++)
            for (int j = 0; j < 2; j++)
                bb[q][j] = *(const bf16x8*)(&Sb[q][(wc * 32 + j * 16 + fr) * 40 + fk]);
        for (int i = 0; i < 2; i++)
            for (int j = 0; j < 2; j++) {
                a_r[i][j]  = mfma16(aa[i], bb[0][j], a_r[i][j]);
                a_r[i][j]  = mfma16(ah[i], bb[3][j], a_r[i][j]);
                a_z[i][j]  = mfma16(aa[i], bb[1][j], a_z[i][j]);
                a_z[i][j]  = mfma16(ah[i], bb[4][j], a_z[i][j]);
                a_in[i][j] = mfma16(aa[i], bb[2][j], a_in[i][j]);
                a_hn[i][j] = mfma16(ah[i], bb[5][j], a_hn[i][j]);
            }
        __syncthreads();
    }

    int cc = lane & 15, cr4 = (lane >> 4) * 4;
    for (int i = 0; i < 2; i++)
        for (int j = 0; j < 2; j++) {
            int gn = n0 + wc * 32 + j * 16 + cc;
            if (gn >= N) continue;
            float br  = bih[gn] + bhh[gn];
            float bz  = bih[1000 + gn] + bhh[1000 + gn];
            float bni = bih[2000 + gn];
            float bnh = bhh[2000 + gn];
            for (int r = 0; r < 4; r++) {
                int gm = m0 + wr * 32 + i * 16 + cr4 + r;
                if (gm >= M) continue;
                float rg = sigmoidf_(a_r[i][j][r] + br);
                float zg = sigmoidf_(a_z[i][j][r] + bz);
                float ng = tanhf(a_in[i][j][r] + bni + rg * (a_hn[i][j][r] + bnh));
                size_t idx = (size_t)gm * DDIM + gn;
                float hp = h_f32 ? ((const float*)hv)[idx] : b2f(((const u16*)hv)[idx]);
                h_out[idx] = f2b((1.0f - zg) * ng + zg * hp);
            }
        }
}

// ---------------------------------------------------------------------------
// out[row] (fp32) = relu(h[row]) . fc_w + fc_b   — one wave per row
// ---------------------------------------------------------------------------
__global__ __launch_bounds__(256) void fc_out(const u16* __restrict__ h,
                                              const float* __restrict__ fw,
                                              const float* __restrict__ fb,
                                              float* __restrict__ out) {
    int row = blockIdx.x * 4 + (threadIdx.x >> 6);
    int lane = threadIdx.x & 63;
    if (row >= N_NODES) return;
    float s = 0.0f;
    for (int i = 0; i < 4; i++) {
        int c = lane + 64 * i;          // chunk of 4 elems
        if (c < 250) {
            uint2 v = *(const uint2*)(h + (size_t)row * DDIM + c * 4);
            float4 w = *(const float4*)(fw + c * 4);
            const u16* pv = (const u16*)&v;
            float h0 = b2f(pv[0]), h1 = b2f(pv[1]), h2 = b2f(pv[2]), h3 = b2f(pv[3]);
            s += (h0 > 0.0f ? h0 : 0.0f) * w.x;
            s += (h1 > 0.0f ? h1 : 0.0f) * w.y;
            s += (h2 > 0.0f ? h2 : 0.0f) * w.z;
            s += (h3 > 0.0f ? h3 : 0.0f) * w.w;
        }
    }
    for (int off = 32; off > 0; off >>= 1) s += __shfl_down(s, off, 64);
    if (lane == 0) out[row] = s + fb[0];
}

// ---------------------------------------------------------------------------
extern "C" void kernel_launch(void* const* d_in, const int* in_sizes, int n_in,
                              void* d_out, int out_size, void* d_ws, size_t ws_size,
                              hipStream_t stream) {
    const float* x   = (const float*)d_in[0];
    const int*   ei  = (const int*)d_in[1];
    const float* ew  = (const float*)d_in[2];
    const float* W   = (const float*)d_in[3];
    const float* wih = (const float*)d_in[4];
    const float* whh = (const float*)d_in[5];
    const float* bih = (const float*)d_in[6];
    const float* bhh = (const float*)d_in[7];
    const float* fw  = (const float*)d_in[8];
    const float* fb  = (const float*)d_in[9];
    float* out = (float*)d_out;

    // workspace layout (178 MB total)
    char* ws = (char*)d_ws;
    u16*   bufA  = (u16*)(ws);                       // 40 MB  (h / m rotation)
    u16*   bufB  = (u16*)(ws + 40000000);            // 40 MB  (m / h rotation)
    float* aggF  = (float*)(ws + 80000000);          // 80 MB  (fp32 scatter dest)
    u16*   Wt    = (u16*)(ws + 160000000);           // 6 MB   (bf16 W^T, 3 layers)
    u16*   wih_b = (u16*)(ws + 166000000);           // 6 MB
    u16*   whh_b = (u16*)(ws + 172000000);           // 6 MB

    // preconvert GRU weights to bf16; transpose+convert per-layer W
    cvt_f32_bf16<<<2930, 256, 0, stream>>>(wih, wih_b, (size_t)3000 * DDIM);
    cvt_f32_bf16<<<2930, 256, 0, stream>>>(whh, whh_b, (size_t)3000 * DDIM);
    transpose_w<<<dim3(32, 32, 3), dim3(32, 8), 0, stream>>>(W, Wt);

    const size_t aggBytes = (size_t)N_NODES * DDIM * sizeof(float);

    // Buffer rotation: l0: m->B, h1->A | l1: m->B, h2->B? no: gru(C, A)->B after
    // m(B) is consumed; l2: m->A (h1 dead), h3->A (m dead). fc(A).
    // layer 0: A-src = x (fp32)
    gemm_bt<<<dim3(157, 8), 256, 0, stream>>>(x, 1, Wt, bufB, N_NODES, DDIM, DDIM);
    hipMemsetAsync(aggF, 0, aggBytes, stream);
    edge_scatter<<<N_EDGES, 256, 0, stream>>>(ei, ew, bufB, aggF);
    gru_fused<<<dim3(313, 16), 256, 0, stream>>>(aggF, x, 1, wih_b, whh_b, bih, bhh, bufA);

    // layer 1: h = bufA (bf16); m -> bufB; h2 -> bufB (m dead after scatter)
    gemm_bt<<<dim3(157, 8), 256, 0, stream>>>(bufA, 0, Wt + 1000000, bufB, N_NODES, DDIM, DDIM);
    hipMemsetAsync(aggF, 0, aggBytes, stream);
    edge_scatter<<<N_EDGES, 256, 0, stream>>>(ei, ew, bufB, aggF);
    gru_fused<<<dim3(313, 16), 256, 0, stream>>>(aggF, bufA, 0, wih_b, whh_b, bih, bhh, bufB);

    // layer 2: h = bufB; m -> bufA (h1 dead); h3 -> bufA (m dead after scatter)
    gemm_bt<<<dim3(157, 8), 256, 0, stream>>>(bufB, 0, Wt + 2000000, bufA, N_NODES, DDIM, DDIM);
    hipMemsetAsync(aggF, 0, aggBytes, stream);
    edge_scatter<<<N_EDGES, 256, 0, stream>>>(ei, ew, bufA, aggF);
    gru_fused<<<dim3(313, 16), 256, 0, stream>>>(aggF, bufB, 0, wih_b, whh_b, bih, bhh, bufA);

    // out = relu(h3) @ fc_w^T + fc_b   (fp32 output)
    fc_out<<<5000, 256, 0, stream>>>(bufA, fw, fb, out);
}

// Round 3
// 2895.241 us; speedup vs baseline: 3.2643x; 3.2643x over previous
//
#include <hip/hip_runtime.h>

typedef unsigned short u16;
typedef unsigned int u32;
typedef __attribute__((ext_vector_type(8))) short bf16x8;
typedef __attribute__((ext_vector_type(4))) float f32x4;

#define N_NODES 20000
#define N_EDGES 160000
#define DDIM    1000

__device__ __forceinline__ float b2f(u16 u) {
    union { u32 i; float f; } v; v.i = ((u32)u) << 16; return v.f;
}
__device__ __forceinline__ u16 f2b(float f) {
    union { float f; u32 i; } v; v.f = f;
    u32 r = v.i + 0x7FFFu + ((v.i >> 16) & 1u);
    return (u16)(r >> 16);
}
__device__ __forceinline__ u32 pack2(float a, float b) {
    return (u32)f2b(a) | ((u32)f2b(b) << 16);
}
__device__ __forceinline__ f32x4 mfma16(bf16x8 a, bf16x8 b, f32x4 c) {
    return __builtin_amdgcn_mfma_f32_16x16x32_bf16(a, b, c, 0, 0, 0);
}
__device__ __forceinline__ float sigmoidf_(float x) { return 1.0f / (1.0f + expf(-x)); }

// ---------------------------------------------------------------------------
// fp32 -> bf16 bulk convert (n % 4 == 0)
// ---------------------------------------------------------------------------
__global__ __launch_bounds__(256) void cvt_f32_bf16(const float* __restrict__ in,
                                                    u16* __restrict__ out, size_t n) {
    size_t i = ((size_t)blockIdx.x * 256 + threadIdx.x) * 4;
    if (i >= n) return;
    float4 v = *(const float4*)(in + i);
    u32 o[2] = {pack2(v.x, v.y), pack2(v.z, v.w)};
    *(uint2*)(out + i) = *(const uint2*)o;
}

// ---------------------------------------------------------------------------
// Transpose weight[l] (fp32 [k][n]) -> Wt (bf16 [n][k]), 3 layers
// ---------------------------------------------------------------------------
__global__ __launch_bounds__(256) void transpose_w(const float* __restrict__ W,
                                                   u16* __restrict__ Wt) {
    __shared__ u16 t[32][33];
    int l = blockIdx.z;
    int nb = blockIdx.x * 32, kb = blockIdx.y * 32;
    int x = threadIdx.x, y = threadIdx.y;  // block (32, 8)
    const float* Wl = W + (size_t)l * 1000000;
    u16* Wtl = Wt + (size_t)l * 1000000;
    for (int i = 0; i < 32; i += 8) {
        int k = kb + y + i, n = nb + x;
        t[y + i][x] = (k < DDIM && n < DDIM) ? f2b(Wl[(size_t)k * DDIM + n]) : (u16)0;
    }
    __syncthreads();
    for (int i = 0; i < 32; i += 8) {
        int n = nb + y + i, k = kb + x;
        if (n < DDIM && k < DDIM) Wtl[(size_t)n * DDIM + k] = t[x][y + i];
    }
}

// ---------------------------------------------------------------------------
// CSR build: count -> scan -> fill. Edge list is constant; build ONCE per call.
// ---------------------------------------------------------------------------
__global__ __launch_bounds__(256) void count_edges(const int* __restrict__ ei,
                                                   int* __restrict__ cnt) {
    int e = blockIdx.x * 256 + threadIdx.x;
    if (e < N_EDGES) atomicAdd(&cnt[ei[N_EDGES + e]], 1);
}

__global__ __launch_bounds__(1024) void scan_offsets(const int* __restrict__ cnt,
                                                     int* __restrict__ ofs) {
    __shared__ int s[1024];
    const int CH = 20;                 // 1024*20 = 20480 >= 20000
    int t = threadIdx.x;
    int base = t * CH;
    int loc[CH];
    int sum = 0;
    for (int j = 0; j < CH; j++) {
        int i = base + j;
        loc[j] = sum;
        sum += (i < N_NODES) ? cnt[i] : 0;
    }
    s[t] = sum;
    __syncthreads();
    for (int d = 1; d < 1024; d <<= 1) {
        int v = (t >= d) ? s[t - d] : 0;
        __syncthreads();
        s[t] += v;
        __syncthreads();
    }
    int excl = s[t] - sum;             // exclusive prefix of this chunk
    for (int j = 0; j < CH; j++) {
        int i = base + j;
        if (i < N_NODES) ofs[i] = excl + loc[j];
    }
    if (t == 0) ofs[N_NODES] = N_EDGES;
}

__global__ __launch_bounds__(256) void fill_buckets(const int* __restrict__ ei,
                                                    const int* __restrict__ ofs,
                                                    int* __restrict__ cur,
                                                    int* __restrict__ bkt) {
    int e = blockIdx.x * 256 + threadIdx.x;
    if (e >= N_EDGES) return;
    int d = ei[N_EDGES + e];
    int pos = atomicAdd(&cur[d], 1);
    bkt[ofs[d] + pos] = e;
}

// ---------------------------------------------------------------------------
// agg[node] = sum_{e: dst=node} m[src(e)] * ew[e]  — one block per node,
// edge metadata staged in LDS, fp32 register accum, bf16 output, NO atomics.
// ---------------------------------------------------------------------------
__global__ __launch_bounds__(256) void node_agg(const int* __restrict__ ei,
                                                const float* __restrict__ ew,
                                                const int* __restrict__ ofs,
                                                const int* __restrict__ bkt,
                                                const u16* __restrict__ m,
                                                u16* __restrict__ agg) {
    __shared__ int   s_src[64];
    __shared__ float s_w[64];
    int node = blockIdx.x;
    int t = threadIdx.x;               // t<250 owns features [4t, 4t+4)
    int beg = ofs[node], end = ofs[node + 1];
    float4 acc = {0.f, 0.f, 0.f, 0.f};
    for (int cb = beg; cb < end; cb += 64) {
        int n = min(64, end - cb);
        if (t < n) {
            int e = bkt[cb + t];
            s_src[t] = ei[e];
            s_w[t]   = ew[e];
        }
        __syncthreads();
        if (t < 250) {
            for (int j = 0; j < n; j++) {
                int src = s_src[j];
                float w = s_w[j];
                uint2 v = *(const uint2*)(m + (size_t)src * DDIM + t * 4);
                const u16* p = (const u16*)&v;
                acc.x += b2f(p[0]) * w;
                acc.y += b2f(p[1]) * w;
                acc.z += b2f(p[2]) * w;
                acc.w += b2f(p[3]) * w;
            }
        }
        __syncthreads();
    }
    if (t < 250) {
        u32 o[2] = {pack2(acc.x, acc.y), pack2(acc.z, acc.w)};
        *(uint2*)(agg + (size_t)node * DDIM + t * 4) = *(const uint2*)o;
    }
}

// ---------------------------------------------------------------------------
// C[M,N] (bf16) = A[M,K] @ Bt[N,K]^T, fp32 accum. A is fp32 (a_f32=1) or bf16.
// 128x128 tile, BK=32, 4 waves of 64x64, mfma 16x16x32 bf16.
// ---------------------------------------------------------------------------
__global__ __launch_bounds__(256) void gemm_bt(const void* __restrict__ Av, int a_f32,
                                               const u16* __restrict__ Bt,
                                               u16* __restrict__ C,
                                               int M, int N, int K) {
    __shared__ u16 As[128 * 40];
    __shared__ u16 Bs[128 * 40];
    int tid = threadIdx.x;
    int wave = tid >> 6, lane = tid & 63;
    int wr = wave >> 1, wc = wave & 1;
    int m0 = blockIdx.x * 128, n0 = blockIdx.y * 128;
    f32x4 acc[4][4] = {};
    int lr = tid >> 2;          // 0..63
    int lk = (tid & 3) * 8;     // k-chunk of 8 within BK=32

    for (int k0 = 0; k0 < K; k0 += 32) {
        int gk = k0 + lk;
        bool kok = (gk < K);    // K % 8 == 0 -> chunk fully in or out
        for (int h = 0; h < 2; h++) {
            int r = lr + h * 64;
            uint4 va = {0, 0, 0, 0}, vb = {0, 0, 0, 0};
            int gm = m0 + r;
            if (gm < M && kok) {
                if (a_f32) {
                    const float* Ap = (const float*)Av + (size_t)gm * K + gk;
                    float4 v0 = *(const float4*)Ap;
                    float4 v1 = *(const float4*)(Ap + 4);
                    va.x = pack2(v0.x, v0.y); va.y = pack2(v0.z, v0.w);
                    va.z = pack2(v1.x, v1.y); va.w = pack2(v1.z, v1.w);
                } else {
                    va = *(const uint4*)((const u16*)Av + (size_t)gm * K + gk);
                }
            }
            *(uint4*)(&As[r * 40 + lk]) = va;
            int gn = n0 + r;
            if (gn < N && kok) vb = *(const uint4*)(Bt + (size_t)gn * K + gk);
            *(uint4*)(&Bs[r * 40 + lk]) = vb;
        }
        __syncthreads();
        int fr = lane & 15, fk = (lane >> 4) * 8;
        bf16x8 af[4], bfv[4];
        for (int i = 0; i < 4; i++)
            af[i] = *(const bf16x8*)(&As[(wr * 64 + i * 16 + fr) * 40 + fk]);
        for (int j = 0; j < 4; j++)
            bfv[j] = *(const bf16x8*)(&Bs[(wc * 64 + j * 16 + fr) * 40 + fk]);
        for (int i = 0; i < 4; i++)
            for (int j = 0; j < 4; j++)
                acc[i][j] = mfma16(af[i], bfv[j], acc[i][j]);
        __syncthreads();
    }

    int cc = lane & 15, cr4 = (lane >> 4) * 4;
    for (int i = 0; i < 4; i++)
        for (int j = 0; j < 4; j++) {
            int gn = n0 + wc * 64 + j * 16 + cc;
            if (gn >= N) continue;
            for (int r = 0; r < 4; r++) {
                int gm = m0 + wr * 64 + i * 16 + cr4 + r;
                if (gm < M) C[(size_t)gm * N + gn] = f2b(acc[i][j][r]);
            }
        }
}

// ---------------------------------------------------------------------------
// Fused GRU: h_out(bf16) = GRU(agg bf16, h (fp32 if h_f32 else bf16)).
// Block tile 64 rows x 64 gate-features; 6 weight slabs (ih/hh x r,z,n) bf16.
// ---------------------------------------------------------------------------
__global__ __launch_bounds__(256) void gru_fused(const u16* __restrict__ aggB,
                                                 const void* __restrict__ hv, int h_f32,
                                                 const u16* __restrict__ wih,
                                                 const u16* __restrict__ whh,
                                                 const float* __restrict__ bih,
                                                 const float* __restrict__ bhh,
                                                 u16* __restrict__ h_out) {
    const int K = DDIM, N = DDIM, M = N_NODES;
    __shared__ u16 Sa[64 * 40];        // agg tile
    __shared__ u16 Sh[64 * 40];        // h tile
    __shared__ u16 Sb[6][64 * 40];     // ih_r, ih_z, ih_n, hh_r, hh_z, hh_n
    int tid = threadIdx.x;
    int wave = tid >> 6, lane = tid & 63;
    int wr = wave >> 1, wc = wave & 1;
    int m0 = blockIdx.x * 64, n0 = blockIdx.y * 64;
    f32x4 a_r[2][2] = {}, a_z[2][2] = {}, a_in[2][2] = {}, a_hn[2][2] = {};
    int lr = tid >> 2;
    int lk = (tid & 3) * 8;

    for (int k0 = 0; k0 < K; k0 += 32) {
        int gk = k0 + lk;
        bool kok = (gk < K);
        {
            int gm = m0 + lr;
            uint4 va = {0, 0, 0, 0}, vh = {0, 0, 0, 0};
            if (gm < M && kok) {
                va = *(const uint4*)(aggB + (size_t)gm * K + gk);
                if (h_f32) {
                    const float* Hp = (const float*)hv + (size_t)gm * K + gk;
                    float4 h0 = *(const float4*)Hp;
                    float4 h1 = *(const float4*)(Hp + 4);
                    vh.x = pack2(h0.x, h0.y); vh.y = pack2(h0.z, h0.w);
                    vh.z = pack2(h1.x, h1.y); vh.w = pack2(h1.z, h1.w);
                } else {
                    vh = *(const uint4*)((const u16*)hv + (size_t)gm * K + gk);
                }
            }
            *(uint4*)(&Sa[lr * 40 + lk]) = va;
            *(uint4*)(&Sh[lr * 40 + lk]) = vh;
        }
        {
            int gn = n0 + lr;
            bool nok = (gn < N);
            for (int g = 0; g < 3; g++) {
                uint4 vi = {0, 0, 0, 0}, vhh = {0, 0, 0, 0};
                if (nok && kok) {
                    vi  = *(const uint4*)(wih + (size_t)(g * 1000 + gn) * K + gk);
                    vhh = *(const uint4*)(whh + (size_t)(g * 1000 + gn) * K + gk);
                }
                *(uint4*)(&Sb[g][lr * 40 + lk]) = vi;
                *(uint4*)(&Sb[3 + g][lr * 40 + lk]) = vhh;
            }
        }
        __syncthreads();
        int fr = lane & 15, fk = (lane >> 4) * 8;
        bf16x8 aa[2], ah[2], bb[6][2];
        for (int i = 0; i < 2; i++) {
            aa[i] = *(const bf16x8*)(&Sa[(wr * 32 + i * 16 + fr) * 40 + fk]);
            ah[i] = *(const bf16x8*)(&Sh[(wr * 32 + i * 16 + fr) * 40 + fk]);
        }
        for (int q = 0; q < 6; q++)
            for (int j = 0; j < 2; j++)
                bb[q][j] = *(const bf16x8*)(&Sb[q][(wc * 32 + j * 16 + fr) * 40 + fk]);
        for (int i = 0; i < 2; i++)
            for (int j = 0; j < 2; j++) {
                a_r[i][j]  = mfma16(aa[i], bb[0][j], a_r[i][j]);
                a_r[i][j]  = mfma16(ah[i], bb[3][j], a_r[i][j]);
                a_z[i][j]  = mfma16(aa[i], bb[1][j], a_z[i][j]);
                a_z[i][j]  = mfma16(ah[i], bb[4][j], a_z[i][j]);
                a_in[i][j] = mfma16(aa[i], bb[2][j], a_in[i][j]);
                a_hn[i][j] = mfma16(ah[i], bb[5][j], a_hn[i][j]);
            }
        __syncthreads();
    }

    int cc = lane & 15, cr4 = (lane >> 4) * 4;
    for (int i = 0; i < 2; i++)
        for (int j = 0; j < 2; j++) {
            int gn = n0 + wc * 32 + j * 16 + cc;
            if (gn >= N) continue;
            float br  = bih[gn] + bhh[gn];
            float bz  = bih[1000 + gn] + bhh[1000 + gn];
            float bni = bih[2000 + gn];
            float bnh = bhh[2000 + gn];
            for (int r = 0; r < 4; r++) {
                int gm = m0 + wr * 32 + i * 16 + cr4 + r;
                if (gm >= M) continue;
                float rg = sigmoidf_(a_r[i][j][r] + br);
                float zg = sigmoidf_(a_z[i][j][r] + bz);
                float ng = tanhf(a_in[i][j][r] + bni + rg * (a_hn[i][j][r] + bnh));
                size_t idx = (size_t)gm * DDIM + gn;
                float hp = h_f32 ? ((const float*)hv)[idx] : b2f(((const u16*)hv)[idx]);
                h_out[idx] = f2b((1.0f - zg) * ng + zg * hp);
            }
        }
}

// ---------------------------------------------------------------------------
// out[row] (fp32) = relu(h[row]) . fc_w + fc_b   — one wave per row
// ---------------------------------------------------------------------------
__global__ __launch_bounds__(256) void fc_out(const u16* __restrict__ h,
                                              const float* __restrict__ fw,
                                              const float* __restrict__ fb,
                                              float* __restrict__ out) {
    int row = blockIdx.x * 4 + (threadIdx.x >> 6);
    int lane = threadIdx.x & 63;
    if (row >= N_NODES) return;
    float s = 0.0f;
    for (int i = 0; i < 4; i++) {
        int c = lane + 64 * i;          // chunk of 4 elems
        if (c < 250) {
            uint2 v = *(const uint2*)(h + (size_t)row * DDIM + c * 4);
            float4 w = *(const float4*)(fw + c * 4);
            const u16* pv = (const u16*)&v;
            float h0 = b2f(pv[0]), h1 = b2f(pv[1]), h2 = b2f(pv[2]), h3 = b2f(pv[3]);
            s += (h0 > 0.0f ? h0 : 0.0f) * w.x;
            s += (h1 > 0.0f ? h1 : 0.0f) * w.y;
            s += (h2 > 0.0f ? h2 : 0.0f) * w.z;
            s += (h3 > 0.0f ? h3 : 0.0f) * w.w;
        }
    }
    for (int off = 32; off > 0; off >>= 1) s += __shfl_down(s, off, 64);
    if (lane == 0) out[row] = s + fb[0];
}

// ---------------------------------------------------------------------------
extern "C" void kernel_launch(void* const* d_in, const int* in_sizes, int n_in,
                              void* d_out, int out_size, void* d_ws, size_t ws_size,
                              hipStream_t stream) {
    const float* x   = (const float*)d_in[0];
    const int*   ei  = (const int*)d_in[1];
    const float* ew  = (const float*)d_in[2];
    const float* W   = (const float*)d_in[3];
    const float* wih = (const float*)d_in[4];
    const float* whh = (const float*)d_in[5];
    const float* bih = (const float*)d_in[6];
    const float* bhh = (const float*)d_in[7];
    const float* fw  = (const float*)d_in[8];
    const float* fb  = (const float*)d_in[9];
    float* out = (float*)d_out;

    // workspace layout (~139 MB)
    char* ws = (char*)d_ws;
    u16* bufA  = (u16*)(ws);                  // 40 MB  (h / m rotation)
    u16* bufB  = (u16*)(ws + 40000000);       // 40 MB  (m / h rotation)
    u16* aggB  = (u16*)(ws + 80000000);       // 40 MB  (bf16 aggregate)
    u16* Wt    = (u16*)(ws + 120000000);      // 6 MB   (bf16 W^T, 3 layers)
    u16* wih_b = (u16*)(ws + 126000000);      // 6 MB
    u16* whh_b = (u16*)(ws + 132000000);      // 6 MB
    int* cnt   = (int*)(ws + 138000000);      // 80 KB
    int* cur   = (int*)(ws + 138080000);      // 80 KB
    int* ofs   = (int*)(ws + 138160000);      // 80 KB + 4
    int* bkt   = (int*)(ws + 138240256);      // 640 KB

    // one-time: weight conversion + CSR build
    cvt_f32_bf16<<<2930, 256, 0, stream>>>(wih, wih_b, (size_t)3000 * DDIM);
    cvt_f32_bf16<<<2930, 256, 0, stream>>>(whh, whh_b, (size_t)3000 * DDIM);
    transpose_w<<<dim3(32, 32, 3), dim3(32, 8), 0, stream>>>(W, Wt);
    hipMemsetAsync(cnt, 0, 160000, stream);   // cnt + cur (adjacent)
    count_edges<<<625, 256, 0, stream>>>(ei, cnt);
    scan_offsets<<<1, 1024, 0, stream>>>(cnt, ofs);
    fill_buckets<<<625, 256, 0, stream>>>(ei, ofs, cur, bkt);

    // layer 0: A-src = x (fp32); m -> bufB; h1 -> bufA
    gemm_bt<<<dim3(157, 8), 256, 0, stream>>>(x, 1, Wt, bufB, N_NODES, DDIM, DDIM);
    node_agg<<<N_NODES, 256, 0, stream>>>(ei, ew, ofs, bkt, bufB, aggB);
    gru_fused<<<dim3(313, 16), 256, 0, stream>>>(aggB, x, 1, wih_b, whh_b, bih, bhh, bufA);

    // layer 1: h = bufA; m -> bufB; h2 -> bufB (m dead after node_agg)
    gemm_bt<<<dim3(157, 8), 256, 0, stream>>>(bufA, 0, Wt + 1000000, bufB, N_NODES, DDIM, DDIM);
    node_agg<<<N_NODES, 256, 0, stream>>>(ei, ew, ofs, bkt, bufB, aggB);
    gru_fused<<<dim3(313, 16), 256, 0, stream>>>(aggB, bufA, 0, wih_b, whh_b, bih, bhh, bufB);

    // layer 2: h = bufB; m -> bufA; h3 -> bufA
    gemm_bt<<<dim3(157, 8), 256, 0, stream>>>(bufB, 0, Wt + 2000000, bufA, N_NODES, DDIM, DDIM);
    node_agg<<<N_NODES, 256, 0, stream>>>(ei, ew, ofs, bkt, bufA, aggB);
    gru_fused<<<dim3(313, 16), 256, 0, stream>>>(aggB, bufB, 0, wih_b, whh_b, bih, bhh, bufA);

    // out = relu(h3) @ fc_w^T + fc_b   (fp32 output)
    fc_out<<<5000, 256, 0, stream>>>(bufA, fw, fb, out);
}